// Round 2
// baseline (379.240 us; speedup 1.0000x reference)
//
#include <hip/hip_runtime.h>
#include <hip/hip_bf16.h>

// Problem constants
constexpr int kH  = 8;     // heads
constexpr int kD  = 16;    // dim per head
constexpr int kHD = 128;   // H*D
constexpr int kN  = 32;    // neighbors
constexpr int kE  = 32;    // edge feature dim
constexpr int kD0 = 128;   // feats0 channels
constexpr int kD1 = 64;    // feats1 channels

constexpr float SCALE0   = 0.25f;                 // 1/sqrt(16)
constexpr float SCALE1   = 0.14433756729740643f;  // 1/sqrt(48)
constexpr float SHARED_S = 0.70710678118654752f;  // sqrt(0.5)
constexpr float NEGV     = -1e9f;

__global__ __launch_bounds__(256) void se3_attn_kernel(
    const float* __restrict__ q0, const float* __restrict__ k0, const float* __restrict__ v0,
    const float* __restrict__ q1, const float* __restrict__ k1, const float* __restrict__ v1,
    const float* __restrict__ feats0, const float* __restrict__ feats1,
    const float* __restrict__ edges,
    const float* __restrict__ Wskv0, const float* __restrict__ Wskv1,
    const float* __restrict__ Wbias, const float* __restrict__ self_bias,
    const float* __restrict__ null_bias,
    const float* __restrict__ nk0, const float* __restrict__ nv0,
    const float* __restrict__ nk1, const float* __restrict__ nv1,
    const float* __restrict__ hw1,
    const float* __restrict__ Wout0, const float* __restrict__ Wout1,
    const int* __restrict__ nmask,
    float* __restrict__ out, int n_total)
{
  const int i = blockIdx.x;
  const int t = threadIdx.x;

  // Padded strides so the sim-phase LDS reads are bank-conflict-free:
  // q0s stride 17, q1s 49, edg 33.
  __shared__ float q0s[kH * 17];       // [h*17 + d]
  __shared__ float q1s[kH * 49];       // [h*49 + d*3 + m]
  __shared__ float f0s[kD0];
  __shared__ float f1s[kD1 * 3];       // [c*3 + m]
  __shared__ float edg[kN * 33];       // [j*33 + e]
  __shared__ float wbT[kE * kH];       // [e*8 + h] (transposed W_bias)
  __shared__ float w1s[kH];            // softplus(head_weights1)
  __shared__ float sk0[kHD], sv0[kHD];
  __shared__ float sk1[kHD * 3], sv1[kHD * 3];
  __shared__ float sc[kH][34];         // scores -> attn (34 = 2 + N)
  __shared__ float o0[kHD];
  __shared__ float o1[kHD * 3];

  // ---------------- Phase 1: stage per-position inputs into LDS ----------------
  {
    if (t < kHD) {
      int h = t >> 4, d = t & 15;
      q0s[h * 17 + d] = q0[(size_t)i * kHD + t];
    }
    for (int u = t; u < kHD * 3; u += 256) {
      int c = u / 3, m = u - c * 3;
      int h = c >> 4, d = c & 15;
      q1s[h * 49 + d * 3 + m] = q1[(size_t)i * kHD * 3 + u];
    }
    if (t < kD0) f0s[t] = feats0[(size_t)i * kD0 + t];
    if (t < kD1 * 3) f1s[t] = feats1[(size_t)i * kD1 * 3 + t];
    for (int u = t; u < kN * kE; u += 256) {
      int j = u >> 5, e = u & 31;
      edg[j * 33 + e] = edges[(size_t)i * kN * kE + u];
    }
    if (t < kH * kE) {
      int h = t >> 5, e = t & 31;
      wbT[e * 8 + h] = Wbias[t];
    }
    if (t < kH) {
      float x = hw1[t];
      w1s[t] = log1pf(expf(x));   // softplus
    }
  }
  __syncthreads();

  // ---------------- Phase 2: self key/value (W_self_kv @ feats) ----------------
  {
    const int o = t;  // rows of W_self_kv: first 128 -> k, last 128 -> v
    // degree 0: dot over 128 channels
    float acc = 0.f;
    const float4* wrow = (const float4*)(Wskv0 + o * kD0);  // 32 x float4
    #pragma unroll
    for (int g = 0; g < 32; ++g) {
      float4 w = wrow[g];
      int cb = g * 4;
      acc += w.x * f0s[cb + 0] + w.y * f0s[cb + 1] + w.z * f0s[cb + 2] + w.w * f0s[cb + 3];
    }
    if (o < kHD) sk0[o] = acc; else sv0[o - kHD] = acc;
    // degree 1: dot over 64 channels, 3 components
    float a0 = 0.f, a1 = 0.f, a2 = 0.f;
    const float4* wrow1 = (const float4*)(Wskv1 + o * kD1);  // 16 x float4
    #pragma unroll
    for (int g = 0; g < 16; ++g) {
      float4 w = wrow1[g];
      float wv[4] = {w.x, w.y, w.z, w.w};
      int cb = g * 4;
      #pragma unroll
      for (int q = 0; q < 4; ++q) {
        int c3 = (cb + q) * 3;
        a0 += wv[q] * f1s[c3 + 0];
        a1 += wv[q] * f1s[c3 + 1];
        a2 += wv[q] * f1s[c3 + 2];
      }
    }
    if (o < kHD) { sk1[o*3+0] = a0; sk1[o*3+1] = a1; sk1[o*3+2] = a2; }
    else { int p = (o - kHD) * 3; sv1[p+0] = a0; sv1[p+1] = a1; sv1[p+2] = a2; }
  }

  // ---------------- Phase 3: neighbor similarities ----------------
  {
    const int j = t >> 3, h = t & 7;  // 32 neighbors x 8 heads
    float bias = 0.f;
    #pragma unroll
    for (int e = 0; e < kE; ++e) bias += edg[j * 33 + e] * wbT[e * 8 + h];
    // sim0: 16 contiguous floats of k0 (4x float4)
    float s0 = 0.f;
    {
      const float4* kr = (const float4*)(k0 + (size_t)(i * kN + j) * kHD + h * kD);
      #pragma unroll
      for (int g = 0; g < 4; ++g) {
        float4 w = kr[g];
        int x = h * 17 + g * 4;
        s0 += w.x * q0s[x + 0] + w.y * q0s[x + 1] + w.z * q0s[x + 2] + w.w * q0s[x + 3];
      }
    }
    // sim1: 48 contiguous floats of k1 (12x float4)
    float s1 = 0.f;
    {
      const float4* kr1 = (const float4*)(k1 + (size_t)(i * kN + j) * kHD * 3 + h * 48);
      #pragma unroll
      for (int g = 0; g < 12; ++g) {
        float4 w = kr1[g];
        int x = h * 49 + g * 4;
        s1 += w.x * q1s[x + 0] + w.y * q1s[x + 1] + w.z * q1s[x + 2] + w.w * q1s[x + 3];
      }
    }
    float total = (s0 * SCALE0 + bias + s1 * SCALE1 * w1s[h]) * SHARED_S;
    bool valid = nmask[(size_t)i * kN + j] != 0;
    sc[h][2 + j] = valid ? total : NEGV;
  }
  __syncthreads();

  // ---------------- Phase 4: null & self similarities ----------------
  if (t < 2 * kH) {
    int h = t & 7;
    bool is_self = t >= kH;
    float s0 = 0.f, s1 = 0.f, bias;
    if (is_self) {
      #pragma unroll
      for (int d = 0; d < kD; ++d) s0 += q0s[h * 17 + d] * sk0[h * kD + d];
      #pragma unroll
      for (int x = 0; x < 48; ++x) s1 += q1s[h * 49 + x] * sk1[h * 48 + x];
      bias = self_bias[h];
    } else {
      #pragma unroll
      for (int d = 0; d < kD; ++d) s0 += q0s[h * 17 + d] * nk0[h * kD + d];
      #pragma unroll
      for (int x = 0; x < 48; ++x) s1 += q1s[h * 49 + x] * nk1[h * 48 + x];
      bias = null_bias[h];
    }
    float total = (s0 * SCALE0 + bias + s1 * SCALE1 * w1s[h]) * SHARED_S;
    sc[h][is_self ? 1 : 0] = total;
  }
  __syncthreads();

  // ---------------- Phase 5: shared softmax over 34 slots (per head) ----------
  if (t < kH) {
    float mx = -1e30f;
    #pragma unroll
    for (int j = 0; j < 34; ++j) mx = fmaxf(mx, sc[t][j]);
    float sum = 0.f;
    #pragma unroll
    for (int j = 0; j < 34; ++j) sum += __expf(sc[t][j] - mx);
    float inv = 1.f / sum;
    #pragma unroll
    for (int j = 0; j < 34; ++j) sc[t][j] = __expf(sc[t][j] - mx) * inv;
  }
  __syncthreads();

  // ---------------- Phase 6: attn-weighted V sums ----------------
  if (t < 64) {
    // degree 0: thread owns channel pair (2t, 2t+1); wave reads 512B/row contig
    const int c0 = 2 * t;
    const int h = t >> 3;
    float ax = sc[h][0] * nv0[c0]     + sc[h][1] * sv0[c0];
    float ay = sc[h][0] * nv0[c0 + 1] + sc[h][1] * sv0[c0 + 1];
    const float2* vp = (const float2*)(v0 + (size_t)i * kN * kHD) + t;
    #pragma unroll
    for (int j = 0; j < kN; ++j) {
      float2 p = vp[j * 64];
      float a = sc[h][2 + j];
      ax += a * p.x; ay += a * p.y;
    }
    o0[c0] = ax; o0[c0 + 1] = ay;
  } else {
    // degree 1: thread owns flat pair (2u, 2u+1) of the 384-elem (c,m) vector.
    const int u = t - 64;            // 0..191
    const int f0i = 2 * u;
    const int h = u / 24;            // = f0i/48
    float ax = sc[h][0] * nv1[f0i]     + sc[h][1] * sv1[f0i];
    float ay = sc[h][0] * nv1[f0i + 1] + sc[h][1] * sv1[f0i + 1];
    const float2* vp = (const float2*)(v1 + (size_t)i * kN * kHD * 3) + u;
    #pragma unroll
    for (int j = 0; j < kN; ++j) {
      float2 p = vp[j * 192];
      float a = sc[h][2 + j];
      ax += a * p.x; ay += a * p.y;
    }
    o1[f0i] = ax; o1[f0i + 1] = ay;
  }
  __syncthreads();

  // ---------------- Phase 7: output projections ----------------
  for (int u = t; u < 320; u += 256) {
    if (u < 128) {
      const int o = u;
      float acc = 0.f;
      const float4* wr = (const float4*)(Wout0 + o * kHD);
      #pragma unroll
      for (int g = 0; g < 32; ++g) {
        float4 w = wr[g];
        int cb = g * 4;
        acc += w.x * o0[cb + 0] + w.y * o0[cb + 1] + w.z * o0[cb + 2] + w.w * o0[cb + 3];
      }
      out[(size_t)i * kHD + o] = acc;
    } else {
      const int v2 = u - 128;        // 0..191 -> (o = v2/3, m = v2%3)
      const int o = v2 / 3, m = v2 - o * 3;
      float acc = 0.f;
      const float4* wr = (const float4*)(Wout1 + o * kHD);
      #pragma unroll
      for (int g = 0; g < 32; ++g) {
        float4 w = wr[g];
        int cb = g * 4;
        acc += w.x * o1[(cb + 0) * 3 + m] + w.y * o1[(cb + 1) * 3 + m]
             + w.z * o1[(cb + 2) * 3 + m] + w.w * o1[(cb + 3) * 3 + m];
      }
      // y1 flat offset: n*HD (=262144 for y0) + i*192 + v2
      out[(size_t)n_total * kHD + (size_t)i * 192 + v2] = acc;
    }
  }
}

extern "C" void kernel_launch(void* const* d_in, const int* in_sizes, int n_in,
                              void* d_out, int out_size, void* d_ws, size_t ws_size,
                              hipStream_t stream) {
  const int n = in_sizes[0] / kHD;  // 2048
  se3_attn_kernel<<<n, 256, 0, stream>>>(
      (const float*)d_in[0],  (const float*)d_in[1],  (const float*)d_in[2],
      (const float*)d_in[3],  (const float*)d_in[4],  (const float*)d_in[5],
      (const float*)d_in[6],  (const float*)d_in[7],  (const float*)d_in[8],
      (const float*)d_in[9],  (const float*)d_in[10], (const float*)d_in[11],
      (const float*)d_in[12], (const float*)d_in[13], (const float*)d_in[14],
      (const float*)d_in[15], (const float*)d_in[16], (const float*)d_in[17],
      (const float*)d_in[18], (const float*)d_in[19], (const float*)d_in[20],
      (const int*)d_in[21],
      (float*)d_out, n);
}